// Round 10
// baseline (11.150 us; speedup 1.0000x reference)
//
#include <hip/hip_runtime.h>
#include <math.h>

#define NPTS 1024
#define CH 256
#define CW 256
#define NSEG 8     // waves per block = point segments (128 pts each)
#define CAP  64    // survivor-record slots per wave (drain invariant: slot < 64)

// Single fused kernel. 1024 blocks x 512 threads; block owns 64 consecutive
// pixels of one row (y uniform). Each of the 8 waves handles 128 points in
// 2 rounds of 64:
//   - fold per-point constants in registers; since y is block-uniform, fold
//     y in too: record = (t10, c0, t11, c1, ca0, ca1, ca2) where
//     c_j = (y-ly)*t0j - lx*t1j. Eval is then t_j(x) = fmaf(x, t1j, c_j) —
//     the SAME fma values the cull computes (bit-identical to prior rounds).
//   - exact-conservative interval cull: t0,t1 linear in x; interval min|t| =
//     max(min(g0,g1), -max(g0,g1), 0) (v_min+v_max+v_max3); skip iff
//     min|t0|+min|t1| >= 1 (m <= 0 over the whole tile).
//   - ballot-compact survivor records into this wave's LDS list (2 float4s).
// Both rounds accumulate into ONE list; single eval pass at the end
// (wave-uniform ds_read_b128 broadcast, 4-way ILP). Wave-uniform drain branch
// (only if >64 survivors accumulate — practically never at ~5% keep) keeps
// worst case correct and bounds every slot index < 64. Zero-pad records
// contribute exactly 0.
__global__ __launch_bounds__(512) void fused_kernel(
    const float* __restrict__ loc,   // (N,2) [y,x]
    const float* __restrict__ mo,    // (N,2,2)
    const float* __restrict__ mso,   // (N,)
    const float* __restrict__ col,   // (N,3)
    const float* __restrict__ alp,   // (N,)
    float* __restrict__ out)
{
    __shared__ float4 recA[NSEG][CAP];     // t10, c0, t11, c1
    __shared__ float4 recB[NSEG][CAP];     // ca0, ca1, ca2, 0
    __shared__ float  part[NSEG][64][3];

    int lane = threadIdx.x & 63;
    int seg  = threadIdx.x >> 6;
    int h    = blockIdx.x >> 2;
    int w0   = (blockIdx.x & 3) << 6;

    float y  = fmaf((float)h,           2.0f/255.0f, -1.0f);
    float x  = fmaf((float)(w0 + lane), 2.0f/255.0f, -1.0f);
    float x0 = fmaf((float)w0,          2.0f/255.0f, -1.0f);
    float x1 = fmaf((float)(w0 + 63),   2.0f/255.0f, -1.0f);

    unsigned long long lt = (1ull << lane) - 1ull;
    int base = 0;
    float ac0 = 0.f, ac1 = 0.f, ac2 = 0.f;

    auto evalList = [&](int cntp) {
        for (int i = 0; i < cntp; i += 4) {
            #pragma unroll
            for (int j = 0; j < 4; ++j) {
                float4 a = recA[seg][i + j];   // uniform addr -> broadcast
                float4 b = recB[seg][i + j];
                float t0 = fmaf(x, a.x, a.y);
                float t1 = fmaf(x, a.z, a.w);
                float m  = fmaxf(1.0f - (fabsf(t0) + fabsf(t1)), 0.0f);
                ac0 = fmaf(b.x, m, ac0);
                ac1 = fmaf(b.y, m, ac1);
                ac2 = fmaf(b.z, m, ac2);
            }
        }
    };

    int segbase = seg << 7;
    #pragma unroll
    for (int r = 0; r < 2; ++r) {
        int n = segbase + (r << 6) + lane;
        // ---- all loads unconditional (batched at top of the wave) ----
        float2 l  = ((const float2*)loc)[n];
        float4 m4 = ((const float4*)mo)[n];       // T00,T01,T10,T11
        float  so = mso[n];
        float  al = alp[n];
        float  ca0 = col[3*n+0] * al;
        float  ca1 = col[3*n+1] * al;
        float  ca2 = col[3*n+2] * al;

        // ---- fused prep, y folded in (registers only) ----
        float  s  = 16.0f * __expf(so);           // sqrt(1024)/2 * exp(off)
        float t00 = 0.5f * (m4.x + s);
        float t01 = 0.5f *  m4.y;
        float t10 = 0.5f *  m4.z;
        float t11 = 0.5f * (m4.w + s);
        float dy  = y - l.x;
        float c0  = fmaf(dy, t00, -(l.y * t10));
        float c1  = fmaf(dy, t01, -(l.y * t11));

        // ---- conservative cull over [x0,x1]: min|t| via min/max/max3 ----
        float g00 = fmaf(x0, t10, c0), g01 = fmaf(x1, t10, c0);
        float g10 = fmaf(x0, t11, c1), g11 = fmaf(x1, t11, c1);
        float m0 = fmaxf(fmaxf(fminf(g00, g01), -fmaxf(g00, g01)), 0.0f);
        float m1 = fmaxf(fmaxf(fminf(g10, g11), -fmaxf(g10, g11)), 0.0f);
        bool keep = (m0 + m1) < 1.0f;
        unsigned long long mk = __ballot(keep);
        int cr = __popcll(mk);

        if (base + cr > 64) {                     // wave-uniform drain (rare)
            int cntp = (base + 3) & ~3;
            if (lane < cntp - base) {
                recA[seg][base + lane] = make_float4(0.f, 0.f, 0.f, 0.f);
                recB[seg][base + lane] = make_float4(0.f, 0.f, 0.f, 0.f);
            }
            evalList(cntp);
            base = 0;
        }
        if (keep) {
            int slot = base + __popcll(mk & lt);
            recA[seg][slot] = make_float4(t10, c0, t11, c1);
            recB[seg][slot] = make_float4(ca0, ca1, ca2, 0.f);
        }
        base += cr;
    }
    {   // single eval pass for the accumulated list
        int cntp = (base + 3) & ~3;
        if (lane < cntp - base) {                 // zero sentinel pad
            recA[seg][base + lane] = make_float4(0.f, 0.f, 0.f, 0.f);
            recB[seg][base + lane] = make_float4(0.f, 0.f, 0.f, 0.f);
        }
        evalList(cntp);
    }

    // ---- cross-segment reduce + sigmoid + store ----
    part[seg][lane][0] = ac0;
    part[seg][lane][1] = ac1;
    part[seg][lane][2] = ac2;
    __syncthreads();
    int t = threadIdx.x;
    if (t < 192) {
        const float* pp = &part[0][0][0];         // [seg] stride = 192 floats
        float sum = 0.f;
        #pragma unroll
        for (int k = 0; k < NSEG; ++k) sum += pp[k * 192 + t];
        out[blockIdx.x * 192 + t] = 1.0f / (1.0f + __expf(-4.0f * sum));
    }
}

extern "C" void kernel_launch(void* const* d_in, const int* in_sizes, int n_in,
                              void* d_out, int out_size, void* d_ws, size_t ws_size,
                              hipStream_t stream) {
    const float* loc = (const float*)d_in[0];
    const float* mo  = (const float*)d_in[1];
    const float* mso = (const float*)d_in[2];
    const float* col = (const float*)d_in[3];
    const float* alp = (const float*)d_in[4];
    float* out = (float*)d_out;
    (void)d_ws; (void)ws_size;

    fused_kernel<<<(CH * CW) / 64, 512, 0, stream>>>(loc, mo, mso, col, alp, out);
}

// Round 11
// 10.005 us; speedup vs baseline: 1.1144x; 1.1144x over previous
//
#include <hip/hip_runtime.h>
#include <math.h>

#define NPTS 1024
#define CH 256
#define CW 256
#define NSEG 8     // waves per block = point segments (128 pts each)
#define CAP  68    // survivor-record slots per wave (drain threshold 64 + pad)

// Single fused kernel (best-known config, = R9). 1024 blocks x 512 threads;
// block owns 64 consecutive pixels of one row (y uniform). Each of the 8
// waves handles 128 points in 2 rounds of 64:
//   - fold per-point constants in registers (incl. color*alpha, hoisted out
//     of the divergent path so all global loads issue unconditionally),
//   - exact-conservative interval cull (t0,t1 linear in x at fixed y;
//     interval min |t| = 0 on sign change else min endpoint magnitude;
//     skip iff min|t0|+min|t1| >= 1  => m <= 0 over the whole tile),
//   - ballot-compact survivor RECORDS into this wave's LDS list.
// Both rounds accumulate into ONE list; a single eval pass runs at the end
// (wave-uniform ds_read_b128 broadcast, 4-way ILP). A wave-uniform drain
// branch (taken only if >64 survivors accumulate — practically never at ~5%
// keep rate) keeps the worst case correct. Zero-pad records contribute
// exactly 0, so output matches the reference up to fp-add reassociation.
__global__ __launch_bounds__(512) void fused_kernel(
    const float* __restrict__ loc,   // (N,2) [y,x]
    const float* __restrict__ mo,    // (N,2,2)
    const float* __restrict__ mso,   // (N,)
    const float* __restrict__ col,   // (N,3)
    const float* __restrict__ alp,   // (N,)
    float* __restrict__ out)
{
    __shared__ float4 recA[NSEG][CAP];     // t00, t10, b0, t01
    __shared__ float4 recB[NSEG][CAP];     // t11, b1, ca0, ca1
    __shared__ float  recC[NSEG][CAP];     // ca2
    __shared__ float  part[NSEG][64][3];

    int lane = threadIdx.x & 63;
    int seg  = threadIdx.x >> 6;
    int h    = blockIdx.x >> 2;
    int w0   = (blockIdx.x & 3) << 6;

    float y  = fmaf((float)h,           2.0f/255.0f, -1.0f);
    float x  = fmaf((float)(w0 + lane), 2.0f/255.0f, -1.0f);
    float x0 = fmaf((float)w0,          2.0f/255.0f, -1.0f);
    float x1 = fmaf((float)(w0 + 63),   2.0f/255.0f, -1.0f);

    unsigned long long lt = (1ull << lane) - 1ull;
    int base = 0;
    float ac0 = 0.f, ac1 = 0.f, ac2 = 0.f;

    auto evalList = [&](int cntp) {
        for (int i = 0; i < cntp; i += 4) {
            #pragma unroll
            for (int j = 0; j < 4; ++j) {
                float4 a = recA[seg][i + j];   // uniform addr -> broadcast
                float4 b = recB[seg][i + j];
                float  c = recC[seg][i + j];
                float t0 = fmaf(x, a.y, fmaf(y, a.x, a.z));
                float t1 = fmaf(x, b.x, fmaf(y, a.w, b.y));
                float m  = fmaxf(1.0f - (fabsf(t0) + fabsf(t1)), 0.0f);
                ac0 = fmaf(b.z, m, ac0);
                ac1 = fmaf(b.w, m, ac1);
                ac2 = fmaf(c,   m, ac2);
            }
        }
    };

    int segbase = seg << 7;
    #pragma unroll
    for (int r = 0; r < 2; ++r) {
        int n = segbase + (r << 6) + lane;
        // ---- all loads unconditional (compiler batches them up top) ----
        float2 l  = ((const float2*)loc)[n];
        float4 m4 = ((const float4*)mo)[n];       // T00,T01,T10,T11
        float  so = mso[n];
        float  al = alp[n];
        float  ca0 = col[3*n+0] * al;
        float  ca1 = col[3*n+1] * al;
        float  ca2 = col[3*n+2] * al;

        // ---- fused prep (registers only) ----
        float  s  = 16.0f * __expf(so);           // sqrt(1024)/2 * exp(off)
        float t00 = 0.5f * (m4.x + s);
        float t01 = 0.5f *  m4.y;
        float t10 = 0.5f *  m4.z;
        float t11 = 0.5f * (m4.w + s);
        float b0  = -(l.x * t00 + l.y * t10);
        float b1  = -(l.x * t01 + l.y * t11);

        // ---- conservative cull over [x0,x1] at fixed y ----
        float c0  = fmaf(y, t00, b0);
        float c1  = fmaf(y, t01, b1);
        float g00 = fmaf(x0, t10, c0), g01 = fmaf(x1, t10, c0);
        float g10 = fmaf(x0, t11, c1), g11 = fmaf(x1, t11, c1);
        float m0 = (g00 * g01 <= 0.0f) ? 0.0f : fminf(fabsf(g00), fabsf(g01));
        float m1 = (g10 * g11 <= 0.0f) ? 0.0f : fminf(fabsf(g10), fabsf(g11));
        bool keep = (m0 + m1) < 1.0f;
        unsigned long long mk = __ballot(keep);
        int cr = __popcll(mk);

        if (base + cr > 64) {                     // wave-uniform drain (rare)
            int cntp = (base + 3) & ~3;
            if (lane < cntp - base) {
                recA[seg][base + lane] = make_float4(0.f, 0.f, 0.f, 0.f);
                recB[seg][base + lane] = make_float4(0.f, 0.f, 0.f, 0.f);
                recC[seg][base + lane] = 0.f;
            }
            evalList(cntp);
            base = 0;
        }
        if (keep) {
            int slot = base + __popcll(mk & lt);
            recA[seg][slot] = make_float4(t00, t10, b0, t01);
            recB[seg][slot] = make_float4(t11, b1, ca0, ca1);
            recC[seg][slot] = ca2;
        }
        base += cr;
    }
    {   // single eval pass for the accumulated list
        int cntp = (base + 3) & ~3;
        if (lane < cntp - base) {                 // zero sentinel pad
            recA[seg][base + lane] = make_float4(0.f, 0.f, 0.f, 0.f);
            recB[seg][base + lane] = make_float4(0.f, 0.f, 0.f, 0.f);
            recC[seg][base + lane] = 0.f;
        }
        evalList(cntp);
    }

    // ---- cross-segment reduce + sigmoid + store ----
    part[seg][lane][0] = ac0;
    part[seg][lane][1] = ac1;
    part[seg][lane][2] = ac2;
    __syncthreads();
    int t = threadIdx.x;
    if (t < 192) {
        const float* pp = &part[0][0][0];         // [seg] stride = 192 floats
        float sum = 0.f;
        #pragma unroll
        for (int k = 0; k < NSEG; ++k) sum += pp[k * 192 + t];
        out[blockIdx.x * 192 + t] = 1.0f / (1.0f + __expf(-4.0f * sum));
    }
}

extern "C" void kernel_launch(void* const* d_in, const int* in_sizes, int n_in,
                              void* d_out, int out_size, void* d_ws, size_t ws_size,
                              hipStream_t stream) {
    const float* loc = (const float*)d_in[0];
    const float* mo  = (const float*)d_in[1];
    const float* mso = (const float*)d_in[2];
    const float* col = (const float*)d_in[3];
    const float* alp = (const float*)d_in[4];
    float* out = (float*)d_out;
    (void)d_ws; (void)ws_size;

    fused_kernel<<<(CH * CW) / 64, 512, 0, stream>>>(loc, mo, mso, col, alp, out);
}